// Round 5
// baseline (1213.027 us; speedup 1.0000x reference)
//
#include <hip/hip_runtime.h>

typedef short bf16x8 __attribute__((ext_vector_type(8)));
typedef float f32x4  __attribute__((ext_vector_type(4)));
typedef unsigned short u16;

#define B_ 4
#define R_ 36
#define RP 48          // r padded to 3 m-tiles of 16
#define C_ 3
#define H_ 384
#define W_ 224
#define KS 64
#define OY 321         // conv-out rows needed (full rows 32..352)
#define OX 161         // conv-out cols needed (full cols 32..192)
#define HC 320
#define WC 160
#define LCOLS 128      // staged cols per WG (64-out-col tiles + 63 halo, rounded)
#define PITCH 72       // row pitch in u16; mult of 8 -> 16B-aligned b128 frags
#define BLKS_PER_BATCH 7200

__device__ __forceinline__ u16 bf16rtn(float v) {
    union { float f; unsigned u; } U; U.f = v;
    unsigned r = U.u + 0x7fffu + ((U.u >> 16) & 1u);
    return (u16)(r >> 16);
}
__device__ __forceinline__ float bf16tof(u16 h) {
    union { float f; unsigned u; } U; U.u = ((unsigned)h) << 16; return U.f;
}

__device__ __forceinline__ float wave_max(float v) {
    #pragma unroll
    for (int off = 32; off > 0; off >>= 1) v = fmaxf(v, __shfl_down(v, off, 64));
    return v;
}
__device__ __forceinline__ float wave_sum(float v) {
    #pragma unroll
    for (int off = 32; off > 0; off >>= 1) v += __shfl_down(v, off, 64);
    return v;
}

// Split fp32 weights into bf16 hi/lo planes, transposed to [b][r48][c][kx][ky], r>=36 zeroed.
__global__ __launch_bounds__(256) void prep_weights(
    const float* __restrict__ wk, u16* __restrict__ wh, u16* __restrict__ wl)
{
    int d = blockIdx.x * 256 + threadIdx.x;           // [0, 4*48*3*64*64)
    int ky = d & 63;
    int kx = (d >> 6) & 63;
    int rc = d >> 12;                                  // (b*48+r)*3 + c
    int c  = rc % 3;
    int br = rc / 3;
    int r  = br % RP;
    int b  = br / RP;
    float v = 0.f;
    if (r < R_) v = wk[(((size_t)(b*R_ + r)*C_ + c)*KS + (size_t)ky)*KS + kx];
    u16 h = bf16rtn(v);
    float lo = v - bf16tof(h);
    wh[d] = h;
    wl[d] = bf16rtn(lo);
}

// Implicit-GEMM conv via MFMA 16x16x32 bf16, 3-product hi/lo split.
// Round-2 loop structure (spill-free register profile: 1 A-set of 24 regs,
// acc 3*NT*4 <= 48 regs). 3 x-tiles of 64 out-cols (NT=4/4/3), LDS 36864 B
// -> 4 WGs/CU resident for latency hiding.
template<int NT>
__device__ __forceinline__ void conv_body(
    const float* __restrict__ in, const u16* __restrict__ wth, const u16* __restrict__ wtl,
    float* __restrict__ out, u16* Lh, u16* Ll, int x0)
{
    const int y0   = blockIdx.y;
    const int b    = blockIdx.z;
    const int t    = threadIdx.x;
    const int w    = t >> 6;
    const int lane = t & 63;
    const int nu   = lane & 15;
    const int q    = lane >> 4;

    f32x4 acc[3][NT];
    #pragma unroll
    for (int mi = 0; mi < 3; mi++)
        #pragma unroll
        for (int n = 0; n < NT; n++)
            acc[mi][n] = (f32x4){0.f, 0.f, 0.f, 0.f};

    const int rp2 = (t >> 3) * 2;   // even row 0..62
    const int fc  = t & 7;

    for (int c = 0; c < C_; c++) {
        __syncthreads();   // protect previous channel's reads
        // ---- stage input rows y0..y0+63, cols x0..x0+127, transposed + bf16-split ----
        const float* src = in + ((size_t)(b*C_ + c))*H_*W_ + (size_t)y0*W_;
        #pragma unroll
        for (int i = 0; i < 4; i++) {
            int c4 = (fc + 8*i) * 4;
            int gx = x0 + c4;
            float4 va = make_float4(0.f,0.f,0.f,0.f), vb = va;
            if (gx < W_) {   // float4 chunks entirely in or out (224 % 4 == 0)
                va = *(const float4*)(src + (size_t)rp2*W_ + gx);
                vb = *(const float4*)(src + (size_t)(rp2+1)*W_ + gx);
            }
            const float* pa = &va.x;
            const float* pb = &vb.x;
            #pragma unroll
            for (int j = 0; j < 4; j++) {
                int col = c4 + j;
                u16 ha = bf16rtn(pa[j]);
                u16 hb = bf16rtn(pb[j]);
                u16 la = bf16rtn(pa[j] - bf16tof(ha));
                u16 lb = bf16rtn(pb[j] - bf16tof(hb));
                *(unsigned*)&Lh[col*PITCH + rp2] = (unsigned)ha | ((unsigned)hb << 16);
                *(unsigned*)&Ll[col*PITCH + rp2] = (unsigned)la | ((unsigned)lb << 16);
            }
        }
        __syncthreads();

        // ---- MFMA; wave w owns kx in {w, w+4, ..., w+60} ----
        #pragma unroll 1
        for (int kxi = 0; kxi < 16; kxi++) {
            int kx = kxi*4 + w;
            #pragma unroll
            for (int kycI = 0; kycI < 2; kycI++) {
                int kyc = kycI * 32;
                bf16x8 Ah[3], Al[3];
                #pragma unroll
                for (int mi = 0; mi < 3; mi++) {
                    size_t off = ((((size_t)(b*RP + mi*16 + nu)*C_ + c)*KS + kx)*KS) + kyc + 8*q;
                    Ah[mi] = *(const bf16x8*)(wth + off);
                    Al[mi] = *(const bf16x8*)(wtl + off);
                }
                const u16* colbase = Lh + (size_t)(nu + kx)*PITCH + kyc + 8*q;
                #pragma unroll
                for (int n = 0; n < NT; n++) {
                    const u16* ph = colbase + n*16*PITCH;
                    bf16x8 Bh = *(const bf16x8*)ph;
                    bf16x8 Bl = *(const bf16x8*)(ph + LCOLS*PITCH);
                    #pragma unroll
                    for (int mi = 0; mi < 3; mi++) {
                        acc[mi][n] = __builtin_amdgcn_mfma_f32_16x16x32_bf16(Ah[mi], Bh, acc[mi][n], 0, 0, 0);
                        acc[mi][n] = __builtin_amdgcn_mfma_f32_16x16x32_bf16(Ah[mi], Bl, acc[mi][n], 0, 0, 0);
                        acc[mi][n] = __builtin_amdgcn_mfma_f32_16x16x32_bf16(Al[mi], Bh, acc[mi][n], 0, 0, 0);
                    }
                }
            }
        }
    }

    // ---- k-split reduction across the 4 waves, chunks of 9 fragments ----
    float* red = (float*)Lh;   // [4 waves][9 frags][64 lanes][4] f32 = 36864 B (== smem)
    const int lsrc = t >> 2;
    const int isrc = t & 3;
    const int F = 3 * NT;
    #pragma unroll 1
    for (int base = 0; base < F; base += 9) {
        __syncthreads();
        #pragma unroll
        for (int k = 0; k < 9; k++) {
            if (base + k < F) {
                int f = base + k;
                *(f32x4*)&red[((w*9 + k)*64 + lane)*4] = acc[f/NT][f%NT];
            }
        }
        __syncthreads();
        #pragma unroll
        for (int k = 0; k < 9; k++) {
            if (base + k < F) {
                float s = red[((0*9+k)*64 + lsrc)*4 + isrc]
                        + red[((1*9+k)*64 + lsrc)*4 + isrc]
                        + red[((2*9+k)*64 + lsrc)*4 + isrc]
                        + red[((3*9+k)*64 + lsrc)*4 + isrc];
                int f  = base + k;
                int r  = (f/NT)*16 + (lsrc >> 4)*4 + isrc;
                int x  = x0 + (f%NT)*16 + (lsrc & 15);
                if (r < R_ && x < OX)
                    out[((size_t)(b*R_ + r)*OY + y0)*OX + x] = s;
            }
        }
    }
}

__global__ __launch_bounds__(256) void conv_mfma(
    const float* __restrict__ in, const u16* __restrict__ wth, const u16* __restrict__ wtl,
    float* __restrict__ out)
{
    __shared__ u16 smem[2 * LCOLS * PITCH];   // 36864 B; reused for reduction
    u16* Lh = smem;
    u16* Ll = smem + LCOLS * PITCH;
    if (blockIdx.x == 0)      conv_body<4>(in, wth, wtl, out, Lh, Ll, 0);
    else if (blockIdx.x == 1) conv_body<4>(in, wth, wtl, out, Lh, Ll, 64);
    else                      conv_body<3>(in, wth, wtl, out, Lh, Ll, 128);
}

// Bilinear resize (iy==i, ix==j for the needed range) + per-block max partials.
__global__ __launch_bounds__(256) void resize_kernel(
    const float* __restrict__ cv, float* __restrict__ out, float* __restrict__ pmax)
{
    const int t = threadIdx.x;
    const int idx = blockIdx.x * 256 + t;
    const int j = idx % WC;
    const int rest = idx / WC;
    const int i = rest % HC;
    const int br = rest / HC;

    float fy = (i + 32.5f) * (1.0f/384.0f);
    float fx = (j + 32.5f) * (1.0f/224.0f);

    const float* p = cv + ((size_t)br*OY + i)*OX + j;
    float v00 = p[0], v01 = p[1], v10 = p[OX], v11 = p[OX+1];
    float v = (1.f-fy)*((1.f-fx)*v00 + fx*v01) + fy*((1.f-fx)*v10 + fx*v11);
    out[idx] = v;

    __shared__ float sm[4];
    float m = wave_max(v);
    if ((t & 63) == 0) sm[t >> 6] = m;
    __syncthreads();
    if (t == 0) pmax[blockIdx.x] = fmaxf(fmaxf(sm[0], sm[1]), fmaxf(sm[2], sm[3]));
}

__global__ __launch_bounds__(256) void reduce_kernel(
    const float* __restrict__ part, float* __restrict__ res, int n, int is_sum)
{
    const int b = blockIdx.x;
    const int t = threadIdx.x;
    const float* p = part + (size_t)b*n;
    float v = is_sum ? 0.f : -3.0e38f;
    for (int k = t; k < n; k += 256) v = is_sum ? (v + p[k]) : fmaxf(v, p[k]);
    __shared__ float sm[4];
    float w = is_sum ? wave_sum(v) : wave_max(v);
    if ((t & 63) == 0) sm[t >> 6] = w;
    __syncthreads();
    if (t == 0) {
        res[b] = is_sum ? (sm[0]+sm[1]+sm[2]+sm[3])
                        : fmaxf(fmaxf(sm[0], sm[1]), fmaxf(sm[2], sm[3]));
    }
}

__global__ __launch_bounds__(256) void exp_kernel(
    float* __restrict__ out, const float* __restrict__ bmax, float* __restrict__ psum)
{
    const int t = threadIdx.x;
    const int idx = blockIdx.x * 256 + t;
    const int b = blockIdx.x / BLKS_PER_BATCH;
    float e = expf(out[idx] - bmax[b]);
    out[idx] = e;
    __shared__ float sm[4];
    float s = wave_sum(e);
    if ((t & 63) == 0) sm[t >> 6] = s;
    __syncthreads();
    if (t == 0) psum[blockIdx.x] = sm[0]+sm[1]+sm[2]+sm[3];
}

__global__ __launch_bounds__(256) void scale_kernel(
    float* __restrict__ out, const float* __restrict__ bsum)
{
    const int idx = blockIdx.x * 256 + threadIdx.x;
    const int b = blockIdx.x / BLKS_PER_BATCH;
    out[idx] = out[idx] / bsum[b];
}

extern "C" void kernel_launch(void* const* d_in, const int* in_sizes, int n_in,
                              void* d_out, int out_size, void* d_ws, size_t ws_size,
                              hipStream_t stream)
{
    const float* logits = (const float*)d_in[0];   // (4,3,384,224) fp32
    const float* wk     = (const float*)d_in[1];   // (144,3,64,64) fp32
    float* out = (float*)d_out;                    // (4,36,320,160) fp32
    char*  wsB = (char*)d_ws;

    // workspace layout (bytes)
    float* convOut = (float*)wsB;                              // 7,442,064 f32 = 29,768,256 B
    u16*   wth     = (u16*)(wsB + 29768256);                   // 2,359,296 u16 = 4,718,592 B
    u16*   wtl     = (u16*)(wsB + 29768256 + 4718592);         // 4,718,592 B
    float* pmax    = (float*)(wsB + 29768256 + 2*4718592);     // 28800 f32
    float* psum    = pmax + 28800;
    float* bmax    = psum + 28800;
    float* bsum    = bmax + 8;

    hipLaunchKernelGGL(prep_weights, dim3(9216),  dim3(256), 0, stream, wk, wth, wtl);
    hipLaunchKernelGGL(conv_mfma,    dim3(3, OY, B_), dim3(256), 0, stream, logits, wth, wtl, convOut);
    hipLaunchKernelGGL(resize_kernel, dim3(28800), dim3(256), 0, stream, convOut, out, pmax);
    hipLaunchKernelGGL(reduce_kernel, dim3(4),     dim3(256), 0, stream, pmax, bmax, BLKS_PER_BATCH, 0);
    hipLaunchKernelGGL(exp_kernel,    dim3(28800), dim3(256), 0, stream, out, bmax, psum);
    hipLaunchKernelGGL(reduce_kernel, dim3(4),     dim3(256), 0, stream, psum, bsum, BLKS_PER_BATCH, 1);
    hipLaunchKernelGGL(scale_kernel,  dim3(28800), dim3(256), 0, stream, out, bsum);
}

// Round 6
// 1161.525 us; speedup vs baseline: 1.0443x; 1.0443x over previous
//
#include <hip/hip_runtime.h>

typedef short bf16x8 __attribute__((ext_vector_type(8)));
typedef float f32x4  __attribute__((ext_vector_type(4)));
typedef unsigned short u16;

#define B_ 4
#define R_ 36
#define RP 48          // r padded to 3 m-tiles of 16
#define C_ 3
#define H_ 384
#define W_ 224
#define KS 64
#define OY 321         // conv-out rows needed (full rows 32..352)
#define OX 161         // conv-out cols needed (full cols 32..192)
#define HC 320
#define WC 160
#define LCOLS 128      // staged cols per WG
#define PITCH 72       // row pitch in u16; mult of 8 -> 16B-aligned b128 frags
#define BLKS_PER_BATCH 7200

__device__ __forceinline__ u16 bf16rtn(float v) {
    union { float f; unsigned u; } U; U.f = v;
    unsigned r = U.u + 0x7fffu + ((U.u >> 16) & 1u);
    return (u16)(r >> 16);
}
__device__ __forceinline__ float bf16tof(u16 h) {
    union { float f; unsigned u; } U; U.u = ((unsigned)h) << 16; return U.f;
}

__device__ __forceinline__ float wave_max(float v) {
    #pragma unroll
    for (int off = 32; off > 0; off >>= 1) v = fmaxf(v, __shfl_down(v, off, 64));
    return v;
}
__device__ __forceinline__ float wave_sum(float v) {
    #pragma unroll
    for (int off = 32; off > 0; off >>= 1) v += __shfl_down(v, off, 64);
    return v;
}

// Split fp32 weights into bf16 hi/lo planes, transposed to [b][r48][c][kx][ky], r>=36 zeroed.
__global__ __launch_bounds__(256) void prep_weights(
    const float* __restrict__ wk, u16* __restrict__ wh, u16* __restrict__ wl)
{
    int d = blockIdx.x * 256 + threadIdx.x;           // [0, 4*48*3*64*64)
    int ky = d & 63;
    int kx = (d >> 6) & 63;
    int rc = d >> 12;                                  // (b*48+r)*3 + c
    int c  = rc % 3;
    int br = rc / 3;
    int r  = br % RP;
    int b  = br / RP;
    float v = 0.f;
    if (r < R_) v = wk[(((size_t)(b*R_ + r)*C_ + c)*KS + (size_t)ky)*KS + kx];
    u16 h = bf16rtn(v);
    float lo = v - bf16tof(h);
    wh[d] = h;
    wl[d] = bf16rtn(lo);
}

// Implicit-GEMM conv via MFMA 16x16x32 bf16, 3-product hi/lo split.
// CRITICAL (round-5 lesson): every index into acc[][] must fold to a
// compile-time constant, or the compiler demotes acc to scratch (524 MB of
// spill traffic). All epilogue loops are fully unrolled.
template<int NT>
__device__ __forceinline__ void conv_body(
    const float* __restrict__ in, const u16* __restrict__ wth, const u16* __restrict__ wtl,
    float* __restrict__ out, u16* Lh, u16* Ll, int x0)
{
    const int y0   = blockIdx.y;
    const int b    = blockIdx.z;
    const int t    = threadIdx.x;
    const int w    = t >> 6;
    const int lane = t & 63;
    const int nu   = lane & 15;
    const int q    = lane >> 4;

    f32x4 acc[3][NT];
    #pragma unroll
    for (int mi = 0; mi < 3; mi++)
        #pragma unroll
        for (int n = 0; n < NT; n++)
            acc[mi][n] = (f32x4){0.f, 0.f, 0.f, 0.f};

    const int rp2 = (t >> 3) * 2;   // even row 0..62
    const int fc  = t & 7;

    for (int c = 0; c < C_; c++) {
        __syncthreads();   // protect previous channel's reads
        // ---- stage input rows y0..y0+63, cols x0..x0+127, transposed + bf16-split ----
        const float* src = in + ((size_t)(b*C_ + c))*H_*W_ + (size_t)y0*W_;
        #pragma unroll
        for (int i = 0; i < 4; i++) {
            int c4 = (fc + 8*i) * 4;
            int gx = x0 + c4;
            float4 va = make_float4(0.f,0.f,0.f,0.f), vb = va;
            if (gx < W_) {   // float4 chunks entirely in or out (224 % 4 == 0)
                va = *(const float4*)(src + (size_t)rp2*W_ + gx);
                vb = *(const float4*)(src + (size_t)(rp2+1)*W_ + gx);
            }
            const float* pa = &va.x;
            const float* pb = &vb.x;
            #pragma unroll
            for (int j = 0; j < 4; j++) {
                int col = c4 + j;
                u16 ha = bf16rtn(pa[j]);
                u16 hb = bf16rtn(pb[j]);
                u16 la = bf16rtn(pa[j] - bf16tof(ha));
                u16 lb = bf16rtn(pb[j] - bf16tof(hb));
                *(unsigned*)&Lh[col*PITCH + rp2] = (unsigned)ha | ((unsigned)hb << 16);
                *(unsigned*)&Ll[col*PITCH + rp2] = (unsigned)la | ((unsigned)lb << 16);
            }
        }
        __syncthreads();

        // ---- MFMA; wave w owns kx in {w, w+4, ..., w+60} ----
        #pragma unroll 1
        for (int kxi = 0; kxi < 16; kxi++) {
            int kx = kxi*4 + w;
            #pragma unroll
            for (int kycI = 0; kycI < 2; kycI++) {
                int kyc = kycI * 32;
                bf16x8 Ah[3], Al[3];
                #pragma unroll
                for (int mi = 0; mi < 3; mi++) {
                    size_t off = ((((size_t)(b*RP + mi*16 + nu)*C_ + c)*KS + kx)*KS) + kyc + 8*q;
                    Ah[mi] = *(const bf16x8*)(wth + off);
                    Al[mi] = *(const bf16x8*)(wtl + off);
                }
                const u16* colbase = Lh + (size_t)(nu + kx)*PITCH + kyc + 8*q;
                #pragma unroll
                for (int n = 0; n < NT; n++) {
                    const u16* ph = colbase + n*16*PITCH;
                    bf16x8 Bh = *(const bf16x8*)ph;
                    bf16x8 Bl = *(const bf16x8*)(ph + LCOLS*PITCH);
                    #pragma unroll
                    for (int mi = 0; mi < 3; mi++) {
                        acc[mi][n] = __builtin_amdgcn_mfma_f32_16x16x32_bf16(Ah[mi], Bh, acc[mi][n], 0, 0, 0);
                        acc[mi][n] = __builtin_amdgcn_mfma_f32_16x16x32_bf16(Ah[mi], Bl, acc[mi][n], 0, 0, 0);
                        acc[mi][n] = __builtin_amdgcn_mfma_f32_16x16x32_bf16(Al[mi], Bh, acc[mi][n], 0, 0, 0);
                    }
                }
            }
        }
    }

    // ---- k-split reduction across the 4 waves: chunks of 6 frags, FULLY unrolled ----
    float* red = (float*)Lh;   // [4 waves][6 frags][64 lanes][4] f32 = 24576 B <= smem
    const int lsrc = t >> 2;
    const int isrc = t & 3;
    constexpr int F = 3 * NT;
    #pragma unroll
    for (int base = 0; base < F; base += 6) {
        __syncthreads();
        #pragma unroll
        for (int k = 0; k < 6; k++) {
            if (base + k < F) {
                *(f32x4*)&red[((w*6 + k)*64 + lane)*4] = acc[(base+k)/NT][(base+k)%NT];
            }
        }
        __syncthreads();
        #pragma unroll
        for (int k = 0; k < 6; k++) {
            if (base + k < F) {
                float s = red[((0*6+k)*64 + lsrc)*4 + isrc]
                        + red[((1*6+k)*64 + lsrc)*4 + isrc]
                        + red[((2*6+k)*64 + lsrc)*4 + isrc]
                        + red[((3*6+k)*64 + lsrc)*4 + isrc];
                int f  = base + k;
                int r  = (f/NT)*16 + (lsrc >> 4)*4 + isrc;
                int x  = x0 + (f%NT)*16 + (lsrc & 15);
                if (r < R_ && x < OX)
                    out[((size_t)(b*R_ + r)*OY + y0)*OX + x] = s;
            }
        }
    }
}

__global__ __launch_bounds__(256) void conv_mfma(
    const float* __restrict__ in, const u16* __restrict__ wth, const u16* __restrict__ wtl,
    float* __restrict__ out)
{
    __shared__ u16 smem[2 * LCOLS * PITCH];   // 36864 B; reused for reduction
    u16* Lh = smem;
    u16* Ll = smem + LCOLS * PITCH;
    if (blockIdx.x == 0)      conv_body<4>(in, wth, wtl, out, Lh, Ll, 0);
    else if (blockIdx.x == 1) conv_body<4>(in, wth, wtl, out, Lh, Ll, 64);
    else                      conv_body<3>(in, wth, wtl, out, Lh, Ll, 128);
}

// Bilinear resize (iy==i, ix==j for the needed range) + per-block max partials.
__global__ __launch_bounds__(256) void resize_kernel(
    const float* __restrict__ cv, float* __restrict__ out, float* __restrict__ pmax)
{
    const int t = threadIdx.x;
    const int idx = blockIdx.x * 256 + t;
    const int j = idx % WC;
    const int rest = idx / WC;
    const int i = rest % HC;
    const int br = rest / HC;

    float fy = (i + 32.5f) * (1.0f/384.0f);
    float fx = (j + 32.5f) * (1.0f/224.0f);

    const float* p = cv + ((size_t)br*OY + i)*OX + j;
    float v00 = p[0], v01 = p[1], v10 = p[OX], v11 = p[OX+1];
    float v = (1.f-fy)*((1.f-fx)*v00 + fx*v01) + fy*((1.f-fx)*v10 + fx*v11);
    out[idx] = v;

    __shared__ float sm[4];
    float m = wave_max(v);
    if ((t & 63) == 0) sm[t >> 6] = m;
    __syncthreads();
    if (t == 0) pmax[blockIdx.x] = fmaxf(fmaxf(sm[0], sm[1]), fmaxf(sm[2], sm[3]));
}

__global__ __launch_bounds__(256) void reduce_kernel(
    const float* __restrict__ part, float* __restrict__ res, int n, int is_sum)
{
    const int b = blockIdx.x;
    const int t = threadIdx.x;
    const float* p = part + (size_t)b*n;
    float v = is_sum ? 0.f : -3.0e38f;
    for (int k = t; k < n; k += 256) v = is_sum ? (v + p[k]) : fmaxf(v, p[k]);
    __shared__ float sm[4];
    float w = is_sum ? wave_sum(v) : wave_max(v);
    if ((t & 63) == 0) sm[t >> 6] = w;
    __syncthreads();
    if (t == 0) {
        res[b] = is_sum ? (sm[0]+sm[1]+sm[2]+sm[3])
                        : fmaxf(fmaxf(sm[0], sm[1]), fmaxf(sm[2], sm[3]));
    }
}

__global__ __launch_bounds__(256) void exp_kernel(
    float* __restrict__ out, const float* __restrict__ bmax, float* __restrict__ psum)
{
    const int t = threadIdx.x;
    const int idx = blockIdx.x * 256 + t;
    const int b = blockIdx.x / BLKS_PER_BATCH;
    float e = expf(out[idx] - bmax[b]);
    out[idx] = e;
    __shared__ float sm[4];
    float s = wave_sum(e);
    if ((t & 63) == 0) sm[t >> 6] = s;
    __syncthreads();
    if (t == 0) psum[blockIdx.x] = sm[0]+sm[1]+sm[2]+sm[3];
}

__global__ __launch_bounds__(256) void scale_kernel(
    float* __restrict__ out, const float* __restrict__ bsum)
{
    const int idx = blockIdx.x * 256 + threadIdx.x;
    const int b = blockIdx.x / BLKS_PER_BATCH;
    out[idx] = out[idx] / bsum[b];
}

extern "C" void kernel_launch(void* const* d_in, const int* in_sizes, int n_in,
                              void* d_out, int out_size, void* d_ws, size_t ws_size,
                              hipStream_t stream)
{
    const float* logits = (const float*)d_in[0];   // (4,3,384,224) fp32
    const float* wk     = (const float*)d_in[1];   // (144,3,64,64) fp32
    float* out = (float*)d_out;                    // (4,36,320,160) fp32
    char*  wsB = (char*)d_ws;

    // workspace layout (bytes)
    float* convOut = (float*)wsB;                              // 7,442,064 f32 = 29,768,256 B
    u16*   wth     = (u16*)(wsB + 29768256);                   // 2,359,296 u16 = 4,718,592 B
    u16*   wtl     = (u16*)(wsB + 29768256 + 4718592);         // 4,718,592 B
    float* pmax    = (float*)(wsB + 29768256 + 2*4718592);     // 28800 f32
    float* psum    = pmax + 28800;
    float* bmax    = psum + 28800;
    float* bsum    = bmax + 8;

    hipLaunchKernelGGL(prep_weights, dim3(9216),  dim3(256), 0, stream, wk, wth, wtl);
    hipLaunchKernelGGL(conv_mfma,    dim3(3, OY, B_), dim3(256), 0, stream, logits, wth, wtl, convOut);
    hipLaunchKernelGGL(resize_kernel, dim3(28800), dim3(256), 0, stream, convOut, out, pmax);
    hipLaunchKernelGGL(reduce_kernel, dim3(4),     dim3(256), 0, stream, pmax, bmax, BLKS_PER_BATCH, 0);
    hipLaunchKernelGGL(exp_kernel,    dim3(28800), dim3(256), 0, stream, out, bmax, psum);
    hipLaunchKernelGGL(reduce_kernel, dim3(4),     dim3(256), 0, stream, psum, bsum, BLKS_PER_BATCH, 1);
    hipLaunchKernelGGL(scale_kernel,  dim3(28800), dim3(256), 0, stream, out, bsum);
}

// Round 7
// 732.877 us; speedup vs baseline: 1.6552x; 1.5849x over previous
//
#include <hip/hip_runtime.h>

typedef short bf16x8 __attribute__((ext_vector_type(8)));
typedef float f32x4  __attribute__((ext_vector_type(4)));
typedef unsigned short u16;

#define B_ 4
#define R_ 36
#define RP 48          // r padded to 3 m-tiles of 16
#define C_ 3
#define H_ 384
#define W_ 224
#define KS 64
#define OY 321         // conv-out rows needed (full rows 32..352)
#define OX 161         // conv-out cols needed (full cols 32..192)
#define HC 320
#define WC 160
#define LCOLS 128      // staged cols per WG
#define PITCH 72       // rows staged per col (64 + 8 halo for second y); u16 units
#define BLKS_PER_BATCH 7200

__device__ __forceinline__ u16 bf16rtn(float v) {
    union { float f; unsigned u; } U; U.f = v;
    unsigned r = U.u + 0x7fffu + ((U.u >> 16) & 1u);
    return (u16)(r >> 16);
}
__device__ __forceinline__ float bf16tof(u16 h) {
    union { float f; unsigned u; } U; U.u = ((unsigned)h) << 16; return U.f;
}

__device__ __forceinline__ float wave_max(float v) {
    #pragma unroll
    for (int off = 32; off > 0; off >>= 1) v = fmaxf(v, __shfl_down(v, off, 64));
    return v;
}
__device__ __forceinline__ float wave_sum(float v) {
    #pragma unroll
    for (int off = 32; off > 0; off >>= 1) v += __shfl_down(v, off, 64);
    return v;
}

// Split fp32 weights into bf16 hi/lo planes, transposed to [b][r48][c][kx][ky], r>=36 zeroed.
__global__ __launch_bounds__(256) void prep_weights(
    const float* __restrict__ wk, u16* __restrict__ wh, u16* __restrict__ wl)
{
    int d = blockIdx.x * 256 + threadIdx.x;           // [0, 4*48*3*64*64)
    int ky = d & 63;
    int kx = (d >> 6) & 63;
    int rc = d >> 12;                                  // (b*48+r)*3 + c
    int c  = rc % 3;
    int br = rc / 3;
    int r  = br % RP;
    int b  = br / RP;
    float v = 0.f;
    if (r < R_) v = wk[(((size_t)(b*R_ + r)*C_ + c)*KS + (size_t)ky)*KS + kx];
    u16 h = bf16rtn(v);
    float lo = v - bf16tof(h);
    wh[d] = h;
    wl[d] = bf16rtn(lo);
}

// Implicit-GEMM conv via MFMA 16x16x32 bf16, 3-product hi/lo split.
// Round-7: each WG computes TWO y rows (y0, y0+8) so every A-fragment load
// (weights, y-independent) feeds 2x the MFMAs; WG count (and per-CU A-path
// cache-line traffic, the r6 regression cause) drops ~2x. The +8 row stride
// keeps second-y LDS B-reads 16B-aligned (offset +8 u16). 72 rows staged.
// All acc indices are compile-time constants (r5 spill lesson).
template<int NT>
__device__ __forceinline__ void conv_body(
    const float* __restrict__ in, const u16* __restrict__ wth, const u16* __restrict__ wtl,
    float* __restrict__ out, u16* Lh, u16* Ll, int x0, int y0, bool has2)
{
    const int b    = blockIdx.z;
    const int t    = threadIdx.x;
    const int w    = t >> 6;
    const int lane = t & 63;
    const int nu   = lane & 15;
    const int q    = lane >> 4;

    f32x4 acc[2][3][NT];
    #pragma unroll
    for (int yi = 0; yi < 2; yi++)
        #pragma unroll
        for (int mi = 0; mi < 3; mi++)
            #pragma unroll
            for (int n = 0; n < NT; n++)
                acc[yi][mi][n] = (f32x4){0.f, 0.f, 0.f, 0.f};

    for (int c = 0; c < C_; c++) {
        __syncthreads();   // protect previous channel's reads
        // ---- stage rows y0..y0+71, cols x0..x0+127, transposed + bf16-split ----
        // 36 row-pairs x 32 float4-cols = 1152 items over 256 threads (5 iters).
        const float* src = in + ((size_t)(b*C_ + c))*H_*W_;
        #pragma unroll
        for (int k = 0; k < 5; k++) {
            int idx = t + 256*k;
            if (idx < 1152) {
                int pair = idx >> 5;         // 0..35
                int r0   = pair * 2;
                int c4   = (idx & 31) * 4;
                int gx   = x0 + c4;
                int gy   = y0 + r0;
                float4 va = make_float4(0.f,0.f,0.f,0.f), vb = va;
                if (gx < W_) {               // float4 chunks entirely in or out
                    if (gy < H_)     va = *(const float4*)(src + (size_t)gy*W_ + gx);
                    if (gy + 1 < H_) vb = *(const float4*)(src + (size_t)(gy+1)*W_ + gx);
                }
                const float* pa = &va.x;
                const float* pb = &vb.x;
                #pragma unroll
                for (int j = 0; j < 4; j++) {
                    int col = c4 + j;
                    u16 ha = bf16rtn(pa[j]);
                    u16 hb = bf16rtn(pb[j]);
                    u16 la = bf16rtn(pa[j] - bf16tof(ha));
                    u16 lb = bf16rtn(pb[j] - bf16tof(hb));
                    *(unsigned*)&Lh[col*PITCH + r0] = (unsigned)ha | ((unsigned)hb << 16);
                    *(unsigned*)&Ll[col*PITCH + r0] = (unsigned)la | ((unsigned)lb << 16);
                }
            }
        }
        __syncthreads();

        // ---- MFMA; wave w owns kx in {w, w+4, ..., w+60} ----
        #pragma unroll 1
        for (int kxi = 0; kxi < 16; kxi++) {
            int kx = kxi*4 + w;
            #pragma unroll
            for (int kycI = 0; kycI < 2; kycI++) {
                int kyc = kycI * 32;
                bf16x8 Ah[3], Al[3];
                #pragma unroll
                for (int mi = 0; mi < 3; mi++) {
                    size_t off = ((((size_t)(b*RP + mi*16 + nu)*C_ + c)*KS + kx)*KS) + kyc + 8*q;
                    Ah[mi] = *(const bf16x8*)(wth + off);
                    Al[mi] = *(const bf16x8*)(wtl + off);
                }
                const u16* colbase = Lh + (size_t)(nu + kx)*PITCH + kyc + 8*q;
                #pragma unroll
                for (int n = 0; n < NT; n++) {
                    const u16* ph = colbase + n*16*PITCH;
                    bf16x8 Bh0 = *(const bf16x8*)ph;
                    bf16x8 Bl0 = *(const bf16x8*)(ph + (size_t)LCOLS*PITCH);
                    #pragma unroll
                    for (int mi = 0; mi < 3; mi++) {
                        acc[0][mi][n] = __builtin_amdgcn_mfma_f32_16x16x32_bf16(Ah[mi], Bh0, acc[0][mi][n], 0, 0, 0);
                        acc[0][mi][n] = __builtin_amdgcn_mfma_f32_16x16x32_bf16(Ah[mi], Bl0, acc[0][mi][n], 0, 0, 0);
                        acc[0][mi][n] = __builtin_amdgcn_mfma_f32_16x16x32_bf16(Al[mi], Bh0, acc[0][mi][n], 0, 0, 0);
                    }
                    bf16x8 Bh1 = *(const bf16x8*)(ph + 8);                        // second y: +8 rows
                    bf16x8 Bl1 = *(const bf16x8*)(ph + (size_t)LCOLS*PITCH + 8);
                    #pragma unroll
                    for (int mi = 0; mi < 3; mi++) {
                        acc[1][mi][n] = __builtin_amdgcn_mfma_f32_16x16x32_bf16(Ah[mi], Bh1, acc[1][mi][n], 0, 0, 0);
                        acc[1][mi][n] = __builtin_amdgcn_mfma_f32_16x16x32_bf16(Ah[mi], Bl1, acc[1][mi][n], 0, 0, 0);
                        acc[1][mi][n] = __builtin_amdgcn_mfma_f32_16x16x32_bf16(Al[mi], Bh1, acc[1][mi][n], 0, 0, 0);
                    }
                }
            }
        }
    }

    // ---- k-split reduction across 4 waves: chunks of 6 frags, FULLY unrolled ----
    float* red = (float*)Lh;   // [4 waves][6 frags][64 lanes][4] f32 = 24576 B <= smem
    const int lsrc = t >> 2;
    const int isrc = t & 3;
    constexpr int F = 2 * 3 * NT;
    #pragma unroll
    for (int base = 0; base < F; base += 6) {
        __syncthreads();
        #pragma unroll
        for (int k = 0; k < 6; k++) {
            if (base + k < F) {
                constexpr int TN = 3 * NT;
                int f = base + k;          // folds to constant under full unroll
                *(f32x4*)&red[((w*6 + k)*64 + lane)*4] = acc[f/TN][(f%TN)/NT][(f%TN)%NT];
            }
        }
        __syncthreads();
        #pragma unroll
        for (int k = 0; k < 6; k++) {
            if (base + k < F) {
                float s = red[((0*6+k)*64 + lsrc)*4 + isrc]
                        + red[((1*6+k)*64 + lsrc)*4 + isrc]
                        + red[((2*6+k)*64 + lsrc)*4 + isrc]
                        + red[((3*6+k)*64 + lsrc)*4 + isrc];
                int f  = base + k;
                int yi = f / (3*NT);
                int mi = (f % (3*NT)) / NT;
                int n  = f % NT;
                int r  = mi*16 + (lsrc >> 4)*4 + isrc;
                int x  = x0 + n*16 + (lsrc & 15);
                int y  = y0 + yi*8;
                if (r < R_ && x < OX && (yi == 0 || has2))
                    out[((size_t)(b*R_ + r)*OY + y)*OX + x] = s;
            }
        }
    }
}

__global__ __launch_bounds__(256) void conv_mfma(
    const float* __restrict__ in, const u16* __restrict__ wth, const u16* __restrict__ wtl,
    float* __restrict__ out)
{
    __shared__ u16 smem[2 * LCOLS * PITCH];   // 36864 B; reused for reduction
    u16* Lh = smem;
    u16* Ll = smem + LCOLS * PITCH;
    // y mapping: by<160 -> y0 = 16*(by>>3) + (by&7), pair (y0, y0+8); by==160 -> y=320 alone
    const int by = blockIdx.y;
    int y0; bool has2;
    if (by < 160) { y0 = ((by >> 3) << 4) + (by & 7); has2 = true; }
    else          { y0 = 320; has2 = false; }

    if (blockIdx.x == 0)      conv_body<4>(in, wth, wtl, out, Lh, Ll, 0,   y0, has2);
    else if (blockIdx.x == 1) conv_body<4>(in, wth, wtl, out, Lh, Ll, 64,  y0, has2);
    else                      conv_body<3>(in, wth, wtl, out, Lh, Ll, 128, y0, has2);
}

// Bilinear resize (iy==i, ix==j for the needed range) + per-block max partials.
__global__ __launch_bounds__(256) void resize_kernel(
    const float* __restrict__ cv, float* __restrict__ out, float* __restrict__ pmax)
{
    const int t = threadIdx.x;
    const int idx = blockIdx.x * 256 + t;
    const int j = idx % WC;
    const int rest = idx / WC;
    const int i = rest % HC;
    const int br = rest / HC;

    float fy = (i + 32.5f) * (1.0f/384.0f);
    float fx = (j + 32.5f) * (1.0f/224.0f);

    const float* p = cv + ((size_t)br*OY + i)*OX + j;
    float v00 = p[0], v01 = p[1], v10 = p[OX], v11 = p[OX+1];
    float v = (1.f-fy)*((1.f-fx)*v00 + fx*v01) + fy*((1.f-fx)*v10 + fx*v11);
    out[idx] = v;

    __shared__ float sm[4];
    float m = wave_max(v);
    if ((t & 63) == 0) sm[t >> 6] = m;
    __syncthreads();
    if (t == 0) pmax[blockIdx.x] = fmaxf(fmaxf(sm[0], sm[1]), fmaxf(sm[2], sm[3]));
}

__global__ __launch_bounds__(256) void reduce_kernel(
    const float* __restrict__ part, float* __restrict__ res, int n, int is_sum)
{
    const int b = blockIdx.x;
    const int t = threadIdx.x;
    const float* p = part + (size_t)b*n;
    float v = is_sum ? 0.f : -3.0e38f;
    for (int k = t; k < n; k += 256) v = is_sum ? (v + p[k]) : fmaxf(v, p[k]);
    __shared__ float sm[4];
    float w = is_sum ? wave_sum(v) : wave_max(v);
    if ((t & 63) == 0) sm[t >> 6] = w;
    __syncthreads();
    if (t == 0) {
        res[b] = is_sum ? (sm[0]+sm[1]+sm[2]+sm[3])
                        : fmaxf(fmaxf(sm[0], sm[1]), fmaxf(sm[2], sm[3]));
    }
}

__global__ __launch_bounds__(256) void exp_kernel(
    float* __restrict__ out, const float* __restrict__ bmax, float* __restrict__ psum)
{
    const int t = threadIdx.x;
    const int idx = blockIdx.x * 256 + t;
    const int b = blockIdx.x / BLKS_PER_BATCH;
    float e = expf(out[idx] - bmax[b]);
    out[idx] = e;
    __shared__ float sm[4];
    float s = wave_sum(e);
    if ((t & 63) == 0) sm[t >> 6] = s;
    __syncthreads();
    if (t == 0) psum[blockIdx.x] = sm[0]+sm[1]+sm[2]+sm[3];
}

__global__ __launch_bounds__(256) void scale_kernel(
    float* __restrict__ out, const float* __restrict__ bsum)
{
    const int idx = blockIdx.x * 256 + threadIdx.x;
    const int b = blockIdx.x / BLKS_PER_BATCH;
    out[idx] = out[idx] / bsum[b];
}

extern "C" void kernel_launch(void* const* d_in, const int* in_sizes, int n_in,
                              void* d_out, int out_size, void* d_ws, size_t ws_size,
                              hipStream_t stream)
{
    const float* logits = (const float*)d_in[0];   // (4,3,384,224) fp32
    const float* wk     = (const float*)d_in[1];   // (144,3,64,64) fp32
    float* out = (float*)d_out;                    // (4,36,320,160) fp32
    char*  wsB = (char*)d_ws;

    // workspace layout (bytes)
    float* convOut = (float*)wsB;                              // 7,442,064 f32 = 29,768,256 B
    u16*   wth     = (u16*)(wsB + 29768256);                   // 2,359,296 u16 = 4,718,592 B
    u16*   wtl     = (u16*)(wsB + 29768256 + 4718592);         // 4,718,592 B
    float* pmax    = (float*)(wsB + 29768256 + 2*4718592);     // 28800 f32
    float* psum    = pmax + 28800;
    float* bmax    = psum + 28800;
    float* bsum    = bmax + 8;

    hipLaunchKernelGGL(prep_weights, dim3(9216),  dim3(256), 0, stream, wk, wth, wtl);
    hipLaunchKernelGGL(conv_mfma,    dim3(3, 161, B_), dim3(256), 0, stream, logits, wth, wtl, convOut);
    hipLaunchKernelGGL(resize_kernel, dim3(28800), dim3(256), 0, stream, convOut, out, pmax);
    hipLaunchKernelGGL(reduce_kernel, dim3(4),     dim3(256), 0, stream, pmax, bmax, BLKS_PER_BATCH, 0);
    hipLaunchKernelGGL(exp_kernel,    dim3(28800), dim3(256), 0, stream, out, bmax, psum);
    hipLaunchKernelGGL(reduce_kernel, dim3(4),     dim3(256), 0, stream, psum, bsum, BLKS_PER_BATCH, 1);
    hipLaunchKernelGGL(scale_kernel,  dim3(28800), dim3(256), 0, stream, out, bsum);
}